// Round 5
// baseline (63.822 us; speedup 1.0000x reference)
//
#include <hip/hip_runtime.h>

// TripletMarginLoss, N=512 anchors, D=128, labels in [0,64).
// loss = sum_{valid (i,j,k)} relu(dm[i,j]-dm[i,k]+1) / (count(> eps) + eps)
// valid(i,j,k) <=> j!=i && lab[j]==lab[i] && lab[k]!=lab[i]
//
// R4 post-mortem: per-dispatch fixed cost (~3-5us) dominates my portion, not
// traffic. 2 dispatches:
//   k1: 256 blocks x 2 anchors each. Each E row float4 is loaded ONCE and
//       dotted against BOTH anchors (halves E traffic vs R2). One {sum,count}
//       pair per block (anchors need no separation in the global sum).
//   k2: 1 block reduces 256 pairs -> out.
// No global atomics/fences anywhere (R3 lesson: ~20us for 512-block
// same-address device atomics).

#define TN 512
#define TD 128
#define TK4 (TD / 4)          // 32 float4 chunks per row
#define TMARGIN 1.0f
#define TEPS 1e-8f

// ---------- Kernel 1: 2 anchors per block, fused dm-row + sweep ------------
__global__ __launch_bounds__(256) void triplet_fused_kernel(
    const float* __restrict__ emb,
    const int* __restrict__ labels,
    float* __restrict__ part)          // part[2b]=sum_b, part[2b+1]=count_b
{
    __shared__ float ei[2][TD];        // the block's two anchor embeddings
    __shared__ float d[2][TN];         // dm rows for both anchors
    __shared__ float pv[2][TN];        // positives + margin, per anchor
    __shared__ int   lab[TN];
    __shared__ int   npos[2];
    __shared__ float red_s[4], red_c[4];

    const int b  = blockIdx.x;
    const int t  = threadIdx.x;
    const int a0 = 2 * b;
    const int a1 = 2 * b + 1;

    // stage both anchors (512B each, coalesced) + labels
    if (t < TD)       ei[0][t] = emb[a0 * TD + t];
    else              ei[1][t - TD] = emb[a1 * TD + (t - TD)];
    for (int j = t; j < TN; j += 256) lab[j] = labels[j];
    if (t < 2) npos[t] = 0;
    __syncthreads();

    // dm rows, coalesced: quad q = t>>2 handles row p*64+q; lane sub = t&3
    // reads float4 chunks sub+4m (64B contiguous per quad per load). Each
    // loaded float4 feeds BOTH anchors' dots. Quad-reduce via 2-step shfl_xor.
    const int q   = t >> 2;
    const int sub = t & 3;
    const float4* E4 = (const float4*)emb;
    const float4* e0 = (const float4*)ei[0];
    const float4* e1 = (const float4*)ei[1];
#pragma unroll
    for (int p = 0; p < 8; ++p) {
        const int row = p * 64 + q;
        const float4* rp = E4 + row * TK4;
        float acc0 = 0.f, acc1 = 0.f;
#pragma unroll
        for (int m = 0; m < 8; ++m) {
            const int c = sub + 4 * m;
            const float4 v  = rp[c];
            const float4 w0 = e0[c];   // broadcast across quads (free)
            const float4 w1 = e1[c];
            acc0 += v.x * w0.x + v.y * w0.y + v.z * w0.z + v.w * w0.w;
            acc1 += v.x * w1.x + v.y * w1.y + v.z * w1.z + v.w * w1.w;
        }
        acc0 += __shfl_xor(acc0, 1);
        acc0 += __shfl_xor(acc0, 2);
        acc1 += __shfl_xor(acc1, 1);
        acc1 += __shfl_xor(acc1, 2);
        if (sub == 0) { d[0][row] = acc0; d[1][row] = acc1; }
    }
    __syncthreads();

    // collect positives for both anchors (LDS atomics, cheap)
    const int lab0 = lab[a0];
    const int lab1 = lab[a1];
    for (int j = t; j < TN; j += 256) {
        const int lj = lab[j];
        if (j != a0 && lj == lab0) {
            int idx = atomicAdd(&npos[0], 1);
            pv[0][idx] = d[0][j] + TMARGIN;
        }
        if (j != a1 && lj == lab1) {
            int idx = atomicAdd(&npos[1], 1);
            pv[1][idx] = d[1][j] + TMARGIN;
        }
    }
    __syncthreads();

    const int np0 = npos[0];
    const int np1 = npos[1];
    float lsum = 0.f, lcnt = 0.f;
    for (int k = t; k < TN; k += 256) {
        const int lk = lab[k];
        if (lk != lab0) {
            const float dn = d[0][k];
            for (int p = 0; p < np0; ++p) {
                const float v = pv[0][p] - dn;
                if (v > 0.f)   lsum += v;
                if (v > TEPS)  lcnt += 1.f;
            }
        }
        if (lk != lab1) {
            const float dn = d[1][k];
            for (int p = 0; p < np1; ++p) {
                const float v = pv[1][p] - dn;
                if (v > 0.f)   lsum += v;
                if (v > TEPS)  lcnt += 1.f;
            }
        }
    }

    // wave(64) shuffle reduction, then cross-wave via LDS
#pragma unroll
    for (int off = 32; off > 0; off >>= 1) {
        lsum += __shfl_down(lsum, off);
        lcnt += __shfl_down(lcnt, off);
    }
    const int wave = t >> 6;
    if ((t & 63) == 0) { red_s[wave] = lsum; red_c[wave] = lcnt; }
    __syncthreads();

    if (t == 0) {
        part[2 * b]     = red_s[0] + red_s[1] + red_s[2] + red_s[3];
        part[2 * b + 1] = red_c[0] + red_c[1] + red_c[2] + red_c[3];
    }
}

// ---------- Kernel 2: reduce 256 pairs, finalize ---------------------------
__global__ __launch_bounds__(256) void triplet_reduce_kernel(
    const float* __restrict__ part, float* __restrict__ out)
{
    __shared__ float red_s[4], red_c[4];
    const int t = threadIdx.x;
    float lsum = part[2 * t];
    float lcnt = part[2 * t + 1];
#pragma unroll
    for (int off = 32; off > 0; off >>= 1) {
        lsum += __shfl_down(lsum, off);
        lcnt += __shfl_down(lcnt, off);
    }
    const int wave = t >> 6;
    if ((t & 63) == 0) { red_s[wave] = lsum; red_c[wave] = lcnt; }
    __syncthreads();
    if (t == 0) {
        const float s = red_s[0] + red_s[1] + red_s[2] + red_s[3];
        const float c = red_c[0] + red_c[1] + red_c[2] + red_c[3];
        out[0] = s / (c + TEPS);
    }
}

extern "C" void kernel_launch(void* const* d_in, const int* in_sizes, int n_in,
                              void* d_out, int out_size, void* d_ws, size_t ws_size,
                              hipStream_t stream) {
    const float* emb  = (const float*)d_in[0];
    const int* labels = (const int*)d_in[1];
    float* out = (float*)d_out;
    float* ws  = (float*)d_ws;

    triplet_fused_kernel<<<256, 256, 0, stream>>>(emb, labels, ws);
    triplet_reduce_kernel<<<1, 256, 0, stream>>>(ws, out);
}